// Round 1
// baseline (58.233 us; speedup 1.0000x reference)
//
#include <hip/hip_runtime.h>

// Problem constants (from reference)
#define C       256      // C_IN == C_OUT
#define KTOP    16.0f
#define NITER   50
#define BATCH   8
#define LENGTH  16384
#define L4      (LENGTH / 4)      // 4096 float4 per row
#define NROWS   (BATCH * C)       // 2048 rows
#define TOTAL4  (NROWS * L4)      // 8,388,608 float4 elements

// ---------------------------------------------------------------------------
// Kernel 1: Dykstra sparse-soft-topk on alpha (n=256) with ONE wave (64 lanes,
// 4 elements per lane, zero barriers), then dv[o] = y[0] * V[0,o].
// Key simplification: p = u - z = (sum(u)-k)/n is the SAME scalar for all
// elements, so p is a per-thread scalar, not a vector.
// ---------------------------------------------------------------------------
__global__ __launch_bounds__(64) void prep_kernel(const float* __restrict__ alpha,
                                                  const float* __restrict__ V,
                                                  float* __restrict__ dv) {
    const int t = threadIdx.x;   // 0..63
    float y[4], q[4];
    float p = 0.0f;
#pragma unroll
    for (int j = 0; j < 4; ++j) {
        y[j] = alpha[t * 4 + j] / 0.01f;   // y0 = s / l
        q[j] = 0.0f;
    }

    for (int it = 0; it < NITER; ++it) {
        float u[4];
        float part = 0.0f;
#pragma unroll
        for (int j = 0; j < 4; ++j) {
            u[j] = y[j] + p;
            part += u[j];
        }
        // wave-wide sum (64 lanes)
#pragma unroll
        for (int m = 1; m < 64; m <<= 1) part += __shfl_xor(part, m);

        const float delta = (part - KTOP) * (1.0f / 256.0f);  // (sum(u)-k)/n
        p = delta;                                            // p = u - z (scalar)
#pragma unroll
        for (int j = 0; j < 4; ++j) {
            const float z = u[j] - delta;
            const float v = z + q[j];
            y[j] = fminf(fmaxf(v, 0.0f), 1.0f);               // clip to [0,1]
            q[j] = v - y[j];
        }
    }

    // only alpha_topk[0] matters: diag_vals[o] = y0 * V[0, o]
    const float y0 = __shfl(y[0], 0);
#pragma unroll
    for (int j = 0; j < 4; ++j) {
        const int o = t * 4 + j;
        dv[o] = y0 * V[o];   // V row 0
    }
}

// ---------------------------------------------------------------------------
// Kernel 2: out[n,o,t] = dv[o]*(x[t-1]+x[t]+x[t+1]) + bias[o], zero-padded.
// float4 vectorized; halos via cross-lane shuffle (a wave never straddles a
// row since L4 % 64 == 0); only lane 0 / lane 63 touch memory for halos.
// ---------------------------------------------------------------------------
__global__ __launch_bounds__(256) void conv_kernel(const float* __restrict__ x,
                                                   const float* __restrict__ dv,
                                                   const float* __restrict__ bias,
                                                   float4* __restrict__ out4) {
    const int idx = blockIdx.x * 256 + threadIdx.x;   // < TOTAL4
    const int row = idx >> 12;        // / L4
    const int j   = idx & (L4 - 1);   // position within row (float4 units)
    const int o   = row & (C - 1);    // channel

    const float d = dv[o];
    const float b = bias[o];

    const float* __restrict__ xr = x + ((size_t)row << 14);  // row * LENGTH
    const float4 v = reinterpret_cast<const float4*>(xr)[j];

    // halo elements: x[4j-1] and x[4j+4]
    float pw = __shfl_up(v.w, 1);     // lane l gets lane l-1's v.w
    float nx = __shfl_down(v.x, 1);   // lane l gets lane l+1's v.x
    const int lane = threadIdx.x & 63;
    if (lane == 0)  pw = (j > 0)      ? xr[4 * j - 1] : 0.0f;
    if (lane == 63) nx = (j < L4 - 1) ? xr[4 * j + 4] : 0.0f;

    float4 r;
    r.x = fmaf(d, pw  + v.x + v.y, b);
    r.y = fmaf(d, v.x + v.y + v.z, b);
    r.z = fmaf(d, v.y + v.z + v.w, b);
    r.w = fmaf(d, v.z + v.w + nx,  b);
    out4[idx] = r;
}

extern "C" void kernel_launch(void* const* d_in, const int* in_sizes, int n_in,
                              void* d_out, int out_size, void* d_ws, size_t ws_size,
                              hipStream_t stream) {
    const float* x     = (const float*)d_in[0];   // [8, 256, 16384]
    const float* V     = (const float*)d_in[1];   // [256, 256]
    const float* alpha = (const float*)d_in[2];   // [256]
    const float* bias  = (const float*)d_in[3];   // [256]
    float* out = (float*)d_out;                   // [8, 256, 16384]
    float* dv  = (float*)d_ws;                    // 256 floats scratch

    prep_kernel<<<1, 64, 0, stream>>>(alpha, V, dv);
    conv_kernel<<<TOTAL4 / 256, 256, 0, stream>>>(x, dv, bias, (float4*)out);
}

// Round 2
// 51.623 us; speedup vs baseline: 1.1280x; 1.1280x over previous
//
#include <hip/hip_runtime.h>

// Problem constants (from reference)
#define C       256      // C_IN == C_OUT
#define KTOP    16.0f
#define NITER   50
#define BATCH   8
#define LENGTH  16384
#define L4      (LENGTH / 4)      // 4096 float4 per row
#define NROWS   (BATCH * C)       // 2048 rows
#define TOTAL4  (NROWS * L4)      // 8,388,608 float4 elements

// ---------------------------------------------------------------------------
// Wave-wide (64-lane) float sum via DPP — pure VALU, no LDS, no waitcnt.
// Canonical chain (LLVM AMDGPU atomic-optimizer / rocPRIM):
//   add row_shr:1,2,4,8  -> each 16-lane row accumulates at its last lane
//   add row_bcast:15 (rows 1,3) -> lane31 = sum(0..31), lane63 = sum(32..63)+...
//   add row_bcast:31 (rows 2,3) -> lane63 = sum(0..63)
// then v_readlane 63 broadcasts the total via SGPR.
// ---------------------------------------------------------------------------
__device__ __forceinline__ float wave_sum_dpp(float x) {
    float t;
    t = __int_as_float(__builtin_amdgcn_update_dpp(0, __float_as_int(x), 0x111, 0xf, 0xf, false)); // row_shr:1
    x += t;
    t = __int_as_float(__builtin_amdgcn_update_dpp(0, __float_as_int(x), 0x112, 0xf, 0xf, false)); // row_shr:2
    x += t;
    t = __int_as_float(__builtin_amdgcn_update_dpp(0, __float_as_int(x), 0x114, 0xf, 0xf, false)); // row_shr:4
    x += t;
    t = __int_as_float(__builtin_amdgcn_update_dpp(0, __float_as_int(x), 0x118, 0xf, 0xf, false)); // row_shr:8
    x += t;
    t = __int_as_float(__builtin_amdgcn_update_dpp(0, __float_as_int(x), 0x142, 0xa, 0xf, false)); // row_bcast:15
    x += t;
    t = __int_as_float(__builtin_amdgcn_update_dpp(0, __float_as_int(x), 0x143, 0xc, 0xf, false)); // row_bcast:31
    x += t;
    return __int_as_float(__builtin_amdgcn_readlane(__float_as_int(x), 63));
}

// ---------------------------------------------------------------------------
// Kernel 1: Dykstra sparse-soft-topk on alpha (n=256) with ONE wave (64 lanes,
// 4 elements per lane), then dv[o] = y[0] * V[0,o].
// p = (sum(u)-k)/n is the SAME scalar for all elements -> scalar register.
// ---------------------------------------------------------------------------
__global__ __launch_bounds__(64) void prep_kernel(const float* __restrict__ alpha,
                                                  const float* __restrict__ V,
                                                  float* __restrict__ dv) {
    const int t = threadIdx.x;   // 0..63
    float y[4], q[4];
    float p = 0.0f;
#pragma unroll
    for (int j = 0; j < 4; ++j) {
        y[j] = alpha[t * 4 + j] / 0.01f;   // y0 = s / l
        q[j] = 0.0f;
    }

    for (int it = 0; it < NITER; ++it) {
        float u[4];
        float part = 0.0f;
#pragma unroll
        for (int j = 0; j < 4; ++j) {
            u[j] = y[j] + p;
            part += u[j];
        }
        const float S = wave_sum_dpp(part);                   // sum over all 256
        const float delta = (S - KTOP) * (1.0f / 256.0f);     // (sum(u)-k)/n
        p = delta;                                            // p = u - z (scalar)
#pragma unroll
        for (int j = 0; j < 4; ++j) {
            const float z = u[j] - delta;
            const float v = z + q[j];
            y[j] = fminf(fmaxf(v, 0.0f), 1.0f);               // clip to [0,1]
            q[j] = v - y[j];
        }
    }

    // only alpha_topk[0] matters: diag_vals[o] = y0 * V[0, o]
    const float y0 = __int_as_float(__builtin_amdgcn_readlane(__float_as_int(y[0]), 0));
#pragma unroll
    for (int j = 0; j < 4; ++j) {
        const int o = t * 4 + j;
        dv[o] = y0 * V[o];   // V row 0
    }
}

// ---------------------------------------------------------------------------
// Kernel 2: out[n,o,t] = dv[o]*(x[t-1]+x[t]+x[t+1]) + bias[o], zero-padded.
// float4 vectorized; halos via cross-lane shuffle (a wave never straddles a
// row since L4 % 64 == 0); only lane 0 / lane 63 touch memory for halos.
// ---------------------------------------------------------------------------
__global__ __launch_bounds__(256) void conv_kernel(const float* __restrict__ x,
                                                   const float* __restrict__ dv,
                                                   const float* __restrict__ bias,
                                                   float4* __restrict__ out4) {
    const int idx = blockIdx.x * 256 + threadIdx.x;   // < TOTAL4
    const int row = idx >> 12;        // / L4
    const int j   = idx & (L4 - 1);   // position within row (float4 units)
    const int o   = row & (C - 1);    // channel

    const float d = dv[o];
    const float b = bias[o];

    const float* __restrict__ xr = x + ((size_t)row << 14);  // row * LENGTH
    const float4 v = reinterpret_cast<const float4*>(xr)[j];

    // halo elements: x[4j-1] and x[4j+4]
    float pw = __shfl_up(v.w, 1);     // lane l gets lane l-1's v.w
    float nx = __shfl_down(v.x, 1);   // lane l gets lane l+1's v.x
    const int lane = threadIdx.x & 63;
    if (lane == 0)  pw = (j > 0)      ? xr[4 * j - 1] : 0.0f;
    if (lane == 63) nx = (j < L4 - 1) ? xr[4 * j + 4] : 0.0f;

    float4 r;
    r.x = fmaf(d, pw  + v.x + v.y, b);
    r.y = fmaf(d, v.x + v.y + v.z, b);
    r.z = fmaf(d, v.y + v.z + v.w, b);
    r.w = fmaf(d, v.z + v.w + nx,  b);
    out4[idx] = r;
}

extern "C" void kernel_launch(void* const* d_in, const int* in_sizes, int n_in,
                              void* d_out, int out_size, void* d_ws, size_t ws_size,
                              hipStream_t stream) {
    const float* x     = (const float*)d_in[0];   // [8, 256, 16384]
    const float* V     = (const float*)d_in[1];   // [256, 256]
    const float* alpha = (const float*)d_in[2];   // [256]
    const float* bias  = (const float*)d_in[3];   // [256]
    float* out = (float*)d_out;                   // [8, 256, 16384]
    float* dv  = (float*)d_ws;                    // 256 floats scratch

    prep_kernel<<<1, 64, 0, stream>>>(alpha, V, dv);
    conv_kernel<<<TOTAL4 / 256, 256, 0, stream>>>(x, dv, bias, (float4*)out);
}